// Round 1
// baseline (208.641 us; speedup 1.0000x reference)
//
#include <hip/hip_runtime.h>

// Inverse Haar DWT (IDWT):
//   a = (LL - HL - LH + HH)/2 -> out[2h  ][2w  ]
//   b = (LL - HL + LH - HH)/2 -> out[2h+1][2w  ]
//   c = (LL + HL - LH - HH)/2 -> out[2h  ][2w+1]
//   d = (LL + HL + LH + HH)/2 -> out[2h+1][2w+1]
// Input:  (N=8, C=64, H=256, W=256) fp32 x4
// Output: (8, 64, 512, 512) fp32

static constexpr int H = 256;
static constexpr int W = 256;
static constexpr long long NC_PLANES = 8LL * 64;            // N*C
static constexpr long long TOTAL_QUADS = NC_PLANES * H * (W / 4); // threads

__global__ __launch_bounds__(256) void idwt_kernel(
    const float* __restrict__ xLL,
    const float* __restrict__ xHL,
    const float* __restrict__ xLH,
    const float* __restrict__ xHH,
    float* __restrict__ out)
{
    long long i = (long long)blockIdx.x * blockDim.x + threadIdx.x;
    if (i >= TOTAL_QUADS) return;

    // decompose: i = ((nc*H + h) * (W/4)) + w4   (all pow2 -> bit ops)
    const int  w4 = (int)(i & 63);          // W/4 = 64
    const long long p = i >> 6;             // plane-row index in [0, NC*H)
    const int  h  = (int)(p & 255);         // H = 256
    const long long nc = p >> 8;

    const long long in_off = p * W + (long long)w4 * 4;

    const float4 ll = *(const float4*)(xLL + in_off);
    const float4 hl = *(const float4*)(xHL + in_off);
    const float4 lh = *(const float4*)(xLH + in_off);
    const float4 hh = *(const float4*)(xHH + in_off);

    // per-element combinations, *0.5
    float a0 = (ll.x - hl.x - lh.x + hh.x) * 0.5f;
    float b0 = (ll.x - hl.x + lh.x - hh.x) * 0.5f;
    float c0 = (ll.x + hl.x - lh.x - hh.x) * 0.5f;
    float d0 = (ll.x + hl.x + lh.x + hh.x) * 0.5f;

    float a1 = (ll.y - hl.y - lh.y + hh.y) * 0.5f;
    float b1 = (ll.y - hl.y + lh.y - hh.y) * 0.5f;
    float c1 = (ll.y + hl.y - lh.y - hh.y) * 0.5f;
    float d1 = (ll.y + hl.y + lh.y + hh.y) * 0.5f;

    float a2 = (ll.z - hl.z - lh.z + hh.z) * 0.5f;
    float b2 = (ll.z - hl.z + lh.z - hh.z) * 0.5f;
    float c2 = (ll.z + hl.z - lh.z - hh.z) * 0.5f;
    float d2 = (ll.z + hl.z + lh.z + hh.z) * 0.5f;

    float a3 = (ll.w - hl.w - lh.w + hh.w) * 0.5f;
    float b3 = (ll.w - hl.w + lh.w - hh.w) * 0.5f;
    float c3 = (ll.w + hl.w - lh.w - hh.w) * 0.5f;
    float d3 = (ll.w + hl.w + lh.w + hh.w) * 0.5f;

    // output: (nc, 2H, 2W); even row = 2h, odd row = 2h+1; col base = 2*w = 8*w4
    const long long row_even = (nc * (2LL * H) + 2LL * h) * (2LL * W) + 8LL * w4;
    const long long row_odd  = row_even + 2LL * W;

    float4 e0 = {a0, c0, a1, c1};
    float4 e1 = {a2, c2, a3, c3};
    float4 o0 = {b0, d0, b1, d1};
    float4 o1 = {b2, d2, b3, d3};

    *(float4*)(out + row_even)     = e0;
    *(float4*)(out + row_even + 4) = e1;
    *(float4*)(out + row_odd)      = o0;
    *(float4*)(out + row_odd + 4)  = o1;
}

extern "C" void kernel_launch(void* const* d_in, const int* in_sizes, int n_in,
                              void* d_out, int out_size, void* d_ws, size_t ws_size,
                              hipStream_t stream) {
    const float* xLL = (const float*)d_in[0];
    const float* xHL = (const float*)d_in[1];
    const float* xLH = (const float*)d_in[2];
    const float* xHH = (const float*)d_in[3];
    float* out = (float*)d_out;

    const long long total = TOTAL_QUADS;           // 8,388,608 threads
    const int block = 256;
    const long long grid = (total + block - 1) / block;  // 32768

    idwt_kernel<<<(unsigned)grid, block, 0, stream>>>(xLL, xHL, xLH, xHH, out);
}

// Round 2
// 186.392 us; speedup vs baseline: 1.1194x; 1.1194x over previous
//
#include <hip/hip_runtime.h>

// Inverse Haar DWT (IDWT):
//   a = (LL - HL - LH + HH)/2 -> out[2h  ][2w  ]
//   b = (LL - HL + LH - HH)/2 -> out[2h+1][2w  ]
//   c = (LL + HL - LH - HH)/2 -> out[2h  ][2w+1]
//   d = (LL + HL + LH + HH)/2 -> out[2h+1][2w+1]
// Input:  (N=8, C=64, H=256, W=256) fp32 x4
// Output: (8, 64, 512, 512) fp32
//
// Round 1: per-thread = 2 input pixels (float2 loads, 8 B/lane) so every
// output float4 store is exactly lane-contiguous (16 B/lane, stride 16 B
// across lanes -> full-density 64 B lines). Round 0's 32 B-strided dwordx4
// stores touched 2x the cache lines at 50% density.

static constexpr int H = 256;
static constexpr int W = 256;
static constexpr long long NC_PLANES = 8LL * 64;                  // N*C
static constexpr long long TOTAL_PAIRS = NC_PLANES * H * (W / 2); // threads = 16,777,216

__global__ __launch_bounds__(256) void idwt_kernel(
    const float* __restrict__ xLL,
    const float* __restrict__ xHL,
    const float* __restrict__ xLH,
    const float* __restrict__ xHH,
    float* __restrict__ out)
{
    long long i = (long long)blockIdx.x * blockDim.x + threadIdx.x;

    // decompose: i = ((nc*H + h) * (W/2)) + w2   (all pow2 -> bit ops)
    const int  w2 = (int)(i & 127);         // W/2 = 128
    const long long p = i >> 7;             // plane-row index in [0, NC*H)
    const int  h  = (int)(p & 255);         // H = 256
    const long long nc = p >> 8;

    const long long in_off = p * W + (long long)w2 * 2;

    const float2 ll = *(const float2*)(xLL + in_off);
    const float2 hl = *(const float2*)(xHL + in_off);
    const float2 lh = *(const float2*)(xLH + in_off);
    const float2 hh = *(const float2*)(xHH + in_off);

    const float a0 = (ll.x - hl.x - lh.x + hh.x) * 0.5f;
    const float b0 = (ll.x - hl.x + lh.x - hh.x) * 0.5f;
    const float c0 = (ll.x + hl.x - lh.x - hh.x) * 0.5f;
    const float d0 = (ll.x + hl.x + lh.x + hh.x) * 0.5f;

    const float a1 = (ll.y - hl.y - lh.y + hh.y) * 0.5f;
    const float b1 = (ll.y - hl.y + lh.y - hh.y) * 0.5f;
    const float c1 = (ll.y + hl.y - lh.y - hh.y) * 0.5f;
    const float d1 = (ll.y + hl.y + lh.y + hh.y) * 0.5f;

    // output: (nc, 2H, 2W); even row = 2h, odd row = 2h+1; col base = 2*(2*w2)
    const long long row_even = (nc * (2LL * H) + 2LL * h) * (2LL * W) + 4LL * w2;
    const long long row_odd  = row_even + 2LL * W;

    const float4 e = {a0, c0, a1, c1};
    const float4 o = {b0, d0, b1, d1};

    *(float4*)(out + row_even) = e;
    *(float4*)(out + row_odd)  = o;
}

extern "C" void kernel_launch(void* const* d_in, const int* in_sizes, int n_in,
                              void* d_out, int out_size, void* d_ws, size_t ws_size,
                              hipStream_t stream) {
    const float* xLL = (const float*)d_in[0];
    const float* xHL = (const float*)d_in[1];
    const float* xLH = (const float*)d_in[2];
    const float* xHH = (const float*)d_in[3];
    float* out = (float*)d_out;

    const int block = 256;
    const long long grid = TOTAL_PAIRS / block;   // 65536, exact

    idwt_kernel<<<(unsigned)grid, block, 0, stream>>>(xLL, xHL, xLH, xHH, out);
}

// Round 4
// 172.854 us; speedup vs baseline: 1.2070x; 1.0783x over previous
//
#include <hip/hip_runtime.h>

// Inverse Haar DWT (IDWT):
//   a = (LL - HL - LH + HH)/2 -> out[2h  ][2w  ]
//   b = (LL - HL + LH - HH)/2 -> out[2h+1][2w  ]
//   c = (LL + HL - LH - HH)/2 -> out[2h  ][2w+1]
//   d = (LL + HL + LH + HH)/2 -> out[2h+1][2w+1]
// Input:  (N=8, C=64, H=256, W=256) fp32 x4
// Output: (8, 64, 512, 512) fp32
//
// Round 1: 2 input pixels/thread -> every output float4 store lane-contiguous.
// Round 3: non-temporal loads+stores via clang ext_vector_type (HIP_vector_type
// structs are rejected by __builtin_nontemporal_*). Streaming data, zero reuse.

typedef float vf2 __attribute__((ext_vector_type(2)));
typedef float vf4 __attribute__((ext_vector_type(4)));

static constexpr int H = 256;
static constexpr int W = 256;
static constexpr long long NC_PLANES = 8LL * 64;                  // N*C
static constexpr long long TOTAL_PAIRS = NC_PLANES * H * (W / 2); // threads = 16,777,216

__global__ __launch_bounds__(256) void idwt_kernel(
    const float* __restrict__ xLL,
    const float* __restrict__ xHL,
    const float* __restrict__ xLH,
    const float* __restrict__ xHH,
    float* __restrict__ out)
{
    long long i = (long long)blockIdx.x * blockDim.x + threadIdx.x;

    // decompose: i = ((nc*H + h) * (W/2)) + w2   (all pow2 -> bit ops)
    const int  w2 = (int)(i & 127);         // W/2 = 128
    const long long p = i >> 7;             // plane-row index in [0, NC*H)
    const int  h  = (int)(p & 255);         // H = 256
    const long long nc = p >> 8;

    const long long in_off = p * W + (long long)w2 * 2;

    const vf2 ll = __builtin_nontemporal_load((const vf2*)(xLL + in_off));
    const vf2 hl = __builtin_nontemporal_load((const vf2*)(xHL + in_off));
    const vf2 lh = __builtin_nontemporal_load((const vf2*)(xLH + in_off));
    const vf2 hh = __builtin_nontemporal_load((const vf2*)(xHH + in_off));

    const float a0 = (ll.x - hl.x - lh.x + hh.x) * 0.5f;
    const float b0 = (ll.x - hl.x + lh.x - hh.x) * 0.5f;
    const float c0 = (ll.x + hl.x - lh.x - hh.x) * 0.5f;
    const float d0 = (ll.x + hl.x + lh.x + hh.x) * 0.5f;

    const float a1 = (ll.y - hl.y - lh.y + hh.y) * 0.5f;
    const float b1 = (ll.y - hl.y + lh.y - hh.y) * 0.5f;
    const float c1 = (ll.y + hl.y - lh.y - hh.y) * 0.5f;
    const float d1 = (ll.y + hl.y + lh.y + hh.y) * 0.5f;

    // output: (nc, 2H, 2W); even row = 2h, odd row = 2h+1; col base = 2*(2*w2)
    const long long row_even = (nc * (2LL * H) + 2LL * h) * (2LL * W) + 4LL * w2;
    const long long row_odd  = row_even + 2LL * W;

    const vf4 e = {a0, c0, a1, c1};
    const vf4 o = {b0, d0, b1, d1};

    __builtin_nontemporal_store(e, (vf4*)(out + row_even));
    __builtin_nontemporal_store(o, (vf4*)(out + row_odd));
}

extern "C" void kernel_launch(void* const* d_in, const int* in_sizes, int n_in,
                              void* d_out, int out_size, void* d_ws, size_t ws_size,
                              hipStream_t stream) {
    const float* xLL = (const float*)d_in[0];
    const float* xHL = (const float*)d_in[1];
    const float* xLH = (const float*)d_in[2];
    const float* xHH = (const float*)d_in[3];
    float* out = (float*)d_out;

    const int block = 256;
    const long long grid = TOTAL_PAIRS / block;   // 65536, exact

    idwt_kernel<<<(unsigned)grid, block, 0, stream>>>(xLL, xHL, xLH, xHH, out);
}